// Round 3
// baseline (131.861 us; speedup 1.0000x reference)
//
#include <hip/hip_runtime.h>
#include <hip/hip_bf16.h>

// LRGCN_Batch — reference returns ONLY h2, so the _relation() path is dead.
// Live math, REASSOCIATED ((A·x)@W == A·(x@W), A = weighted-mean gather op):
//   Y1 = x @ W1            (dense GEMM 50000x128x128)
//   h1 = elu(gather_mean(Y1, adj1_idx, adj1_w2))
//   Y2 = h1 @ W2           (dense GEMM 50000x128x64)
//   out = gather_mean(Y2, adj2_idx, adj2_w2)
// Pure fp32 (no fp32 MFMA on CDNA4; threshold 7.7e-4 abs makes bf16 risky).

#define NN   50000
#define KNBR 16
#define NF   128   // NFEAT == NHID
#define NC   64    // NCLASS

// ---------------- dense GEMM: C[M x BN_] = A[M x 128] @ B[128 x BN_] --------
// BM=128 rows/block, BK=64 (2 chunks), 256 threads.
// Per-thread tile: 8 rows x CPT cols (CPT = BN_/16 = 8 or 4).
// A_s natural layout [BM][BK+2] (pad: b64-aligned stores, 2-way-max reads).
// B_s natural [BK][BN_] (b128 both ways). ~1-1.5 B LDS traffic / FMA.
template <int BN_>
__global__ __launch_bounds__(256, 2) void gemm_k128(
    const float* __restrict__ A, const float* __restrict__ B,
    float* __restrict__ C, int M) {
  constexpr int BM = 128, BK = 64;
  constexpr int CPT = BN_ / 16;
  __shared__ float A_s[BM][BK + 2];
  __shared__ float B_s[BK][BN_];

  const int t   = threadIdx.x;
  const int bm0 = blockIdx.x * BM;
  const int mt  = t >> 4;          // 0..15
  const int ct  = t & 15;          // 0..15
  const int m0  = mt * 8;
  const int c0  = ct * CPT;

  float acc[8][CPT];
#pragma unroll
  for (int i = 0; i < 8; ++i)
#pragma unroll
    for (int j = 0; j < CPT; ++j) acc[i][j] = 0.f;

  const float4* A4 = reinterpret_cast<const float4*>(A);
  const float4* B4 = reinterpret_cast<const float4*>(B);

  for (int kc = 0; kc < 2; ++kc) {
    __syncthreads();
    {  // stage A chunk: 128 rows x 64 cols
      const int k4 = t & 15, mr = t >> 4;
#pragma unroll
      for (int p = 0; p < 8; ++p) {
        const int m  = mr + p * 16;
        int row = bm0 + m; if (row >= M) row = M - 1;   // clamp (dup row, safe)
        const float4 v = A4[row * (NF / 4) + kc * 16 + k4];
        float2* dst = reinterpret_cast<float2*>(&A_s[m][k4 * 4]);
        dst[0] = make_float2(v.x, v.y);
        dst[1] = make_float2(v.z, v.w);
      }
    }
    if (BN_ == 128) {  // stage B chunk: 64 x 128
      const int c4 = t & 31, fr = t >> 5;
#pragma unroll
      for (int p = 0; p < 8; ++p) {
        const int f = fr + p * 8;
        *reinterpret_cast<float4*>(&B_s[f][c4 * 4]) =
            B4[(kc * BK + f) * (BN_ / 4) + c4];
      }
    } else {           // stage B chunk: 64 x 64
      const int c4 = t & 15, fr = t >> 4;
#pragma unroll
      for (int p = 0; p < 4; ++p) {
        const int f = fr + p * 16;
        *reinterpret_cast<float4*>(&B_s[f][c4 * 4]) =
            B4[(kc * BK + f) * (BN_ / 4) + c4];
      }
    }
    __syncthreads();

#pragma unroll 2
    for (int f = 0; f < BK; ++f) {
      float a[8];
#pragma unroll
      for (int i = 0; i < 8; ++i) a[i] = A_s[m0 + i][f];  // broadcast reads
      float b[CPT];
#pragma unroll
      for (int j4 = 0; j4 < CPT / 4; ++j4) {
        const float4 bv =
            *reinterpret_cast<const float4*>(&B_s[f][c0 + j4 * 4]);
        b[j4 * 4 + 0] = bv.x; b[j4 * 4 + 1] = bv.y;
        b[j4 * 4 + 2] = bv.z; b[j4 * 4 + 3] = bv.w;
      }
#pragma unroll
      for (int i = 0; i < 8; ++i)
#pragma unroll
        for (int j = 0; j < CPT; ++j) acc[i][j] += a[i] * b[j];
    }
  }

  float4* C4 = reinterpret_cast<float4*>(C);
#pragma unroll
  for (int i = 0; i < 8; ++i) {
    const int row = bm0 + m0 + i;
    if (row < M) {
#pragma unroll
      for (int j4 = 0; j4 < CPT / 4; ++j4) {
        C4[row * (BN_ / 4) + c0 / 4 + j4] =
            make_float4(acc[i][j4 * 4 + 0], acc[i][j4 * 4 + 1],
                        acc[i][j4 * 4 + 2], acc[i][j4 * 4 + 3]);
      }
    }
  }
}

// ---------------- gather-mean, width 128 (optionally fused elu) -------------
// NPB=16 nodes/block, 256 threads: 8 groups x 32 lanes, 2 nodes/group.
template <bool ELU>
__global__ void gather_mean_128(const float* __restrict__ Y,
                                const int* __restrict__ idx,
                                const float* __restrict__ w,
                                float* __restrict__ out) {
  __shared__ int   idx_s[16][KNBR];
  __shared__ float w_s[16][KNBR];
  const int t = threadIdx.x, n0 = blockIdx.x * 16;
  {
    const int node = t >> 4, k = t & 15;
    const int g = (n0 + node) * (KNBR + 1) + 1 + k;
    idx_s[node][k] = idx[g];
    w_s[node][k]   = w[g];
  }
  __syncthreads();

  const float4* Y4 = reinterpret_cast<const float4*>(Y);
  const int grp = t >> 5, l = t & 31;
#pragma unroll
  for (int i = 0; i < 2; ++i) {
    const int n = grp * 2 + i;
    float ax = 0.f, ay = 0.f, az = 0.f, aw = 0.f;
#pragma unroll
    for (int k = 0; k < KNBR; ++k) {
      const float4 v  = Y4[idx_s[n][k] * (NF / 4) + l];
      const float  wv = w_s[n][k];
      ax += wv * v.x; ay += wv * v.y; az += wv * v.z; aw += wv * v.w;
    }
    ax *= 1.f / KNBR; ay *= 1.f / KNBR; az *= 1.f / KNBR; aw *= 1.f / KNBR;
    if (ELU) {
      ax = ax > 0.f ? ax : expm1f(ax);
      ay = ay > 0.f ? ay : expm1f(ay);
      az = az > 0.f ? az : expm1f(az);
      aw = aw > 0.f ? aw : expm1f(aw);
    }
    reinterpret_cast<float4*>(out)[(n0 + n) * (NF / 4) + l] =
        make_float4(ax, ay, az, aw);
  }
}

// ---------------- gather-mean, width 64 -------------------------------------
// NPB=16 nodes/block, 256 threads: 16 groups x 16 lanes, 1 node/group.
__global__ void gather_mean_64(const float* __restrict__ Y,
                               const int* __restrict__ idx,
                               const float* __restrict__ w,
                               float* __restrict__ out) {
  __shared__ int   idx_s[16][KNBR];
  __shared__ float w_s[16][KNBR];
  const int t = threadIdx.x, n0 = blockIdx.x * 16;
  {
    const int node = t >> 4, k = t & 15;
    const int g = (n0 + node) * (KNBR + 1) + 1 + k;
    idx_s[node][k] = idx[g];
    w_s[node][k]   = w[g];
  }
  __syncthreads();

  const float4* Y4 = reinterpret_cast<const float4*>(Y);
  const int n = t >> 4, l = t & 15;
  float ax = 0.f, ay = 0.f, az = 0.f, aw = 0.f;
#pragma unroll
  for (int k = 0; k < KNBR; ++k) {
    const float4 v  = Y4[idx_s[n][k] * (NC / 4) + l];
    const float  wv = w_s[n][k];
    ax += wv * v.x; ay += wv * v.y; az += wv * v.z; aw += wv * v.w;
  }
  reinterpret_cast<float4*>(out)[(n0 + n) * (NC / 4) + l] = make_float4(
      ax * (1.f / KNBR), ay * (1.f / KNBR), az * (1.f / KNBR),
      aw * (1.f / KNBR));
}

extern "C" void kernel_launch(void* const* d_in, const int* in_sizes, int n_in,
                              void* d_out, int out_size, void* d_ws,
                              size_t ws_size, hipStream_t stream) {
  // 0:x 1:adj1_idx 2:adj1_w1(dead) 3:adj1_w2 4:adj2_idx 5:adj2_w1(dead)
  // 6:adj2_w2 7:W1 8:W2 9..18: relation params (ALL dead)
  const float* x   = (const float*)d_in[0];
  const int*   a1i = (const int*)d_in[1];
  const float* a1w = (const float*)d_in[3];
  const int*   a2i = (const int*)d_in[4];
  const float* a2w = (const float*)d_in[6];
  const float* W1  = (const float*)d_in[7];
  const float* W2  = (const float*)d_in[8];
  float*       out = (float*)d_out;

  float* Y1 = (float*)d_ws;                                 // 25.6 MB
  float* h1 = (float*)((char*)d_ws + (size_t)NN * NF * 4);  // 25.6 MB
  float* Y2 = Y1;  // reuse Y1's region (12.8 MB needed; Y1 dead by then)

  const int gemm_grid = (NN + 127) / 128;  // 391
  gemm_k128<NF><<<gemm_grid, 256, 0, stream>>>(x, W1, Y1, NN);
  gather_mean_128<true><<<NN / 16, 256, 0, stream>>>(Y1, a1i, a1w, h1);
  gemm_k128<NC><<<gemm_grid, 256, 0, stream>>>(h1, W2, Y2, NN);
  gather_mean_64<<<NN / 16, 256, 0, stream>>>(Y2, a2i, a2w, out);
}

// Round 4
// 92.373 us; speedup vs baseline: 1.4275x; 1.4275x over previous
//
#include <hip/hip_runtime.h>
#include <hip/hip_bf16.h>

// LRGCN_Batch — reference returns ONLY h2, so the _relation() path is dead.
// Live math, REASSOCIATED ((A·x)@W == A·(x@W), A = weighted-mean gather op):
//   Y1 = x @ W1            (dense GEMM 50000x128x128, fp32 math, bf16 store)
//   h1 = elu(gather_mean(Y1, adj1_idx, adj1_w2))        (fp32)
//   Y2 = h1 @ W2           (dense GEMM 50000x128x64, fp32 math, bf16 store)
//   out = gather_mean(Y2, adj2_idx, adj2_w2)            (fp32 out)
// R4 change: Y1/Y2 stored bf16 -> gather traffic halves AND Y1 (12.8MB)
// roughly doubles per-XCD L2 coverage. Gathers are the measured bottleneck
// (57us, FETCH 174MB, VALUBusy 15%). Dense paths stay fp32: quantization is
// one rounding of Y per layer; propagated absmax contribution ~1e-4 vs
// 7.7e-4 threshold (fp32 baseline was 6.1e-5).

#define NN   50000
#define KNBR 16
#define NF   128   // NFEAT == NHID
#define NC   64    // NCLASS

static __device__ __forceinline__ unsigned short f2bf(float f) {
  __hip_bfloat16 h = __float2bfloat16(f);  // RNE
  return reinterpret_cast<unsigned short&>(h);
}
static __device__ __forceinline__ float bflo(unsigned int u) {
  return __uint_as_float(u << 16);
}
static __device__ __forceinline__ float bfhi(unsigned int u) {
  return __uint_as_float(u & 0xffff0000u);
}

// ---------------- dense GEMM: C[M x BN_] = A[M x 128] @ B[128 x BN_] --------
// fp32 compute, bf16 output. BM=128 rows/block, BK=64, 256 threads,
// per-thread 8 rows x CPT cols (CPT = BN_/16).
template <int BN_>
__global__ __launch_bounds__(256, 2) void gemm_k128_bf16out(
    const float* __restrict__ A, const float* __restrict__ B,
    unsigned short* __restrict__ C, int M) {
  constexpr int BM = 128, BK = 64;
  constexpr int CPT = BN_ / 16;
  __shared__ float A_s[BM][BK + 2];
  __shared__ float B_s[BK][BN_];

  const int t   = threadIdx.x;
  const int bm0 = blockIdx.x * BM;
  const int mt  = t >> 4;          // 0..15
  const int ct  = t & 15;          // 0..15
  const int m0  = mt * 8;
  const int c0  = ct * CPT;

  float acc[8][CPT];
#pragma unroll
  for (int i = 0; i < 8; ++i)
#pragma unroll
    for (int j = 0; j < CPT; ++j) acc[i][j] = 0.f;

  const float4* A4 = reinterpret_cast<const float4*>(A);
  const float4* B4 = reinterpret_cast<const float4*>(B);

  for (int kc = 0; kc < 2; ++kc) {
    __syncthreads();
    {  // stage A chunk: 128 rows x 64 cols
      const int k4 = t & 15, mr = t >> 4;
#pragma unroll
      for (int p = 0; p < 8; ++p) {
        const int m  = mr + p * 16;
        int row = bm0 + m; if (row >= M) row = M - 1;   // clamp (dup, safe)
        const float4 v = A4[row * (NF / 4) + kc * 16 + k4];
        float2* dst = reinterpret_cast<float2*>(&A_s[m][k4 * 4]);
        dst[0] = make_float2(v.x, v.y);
        dst[1] = make_float2(v.z, v.w);
      }
    }
    if (BN_ == 128) {  // stage B chunk: 64 x 128
      const int c4 = t & 31, fr = t >> 5;
#pragma unroll
      for (int p = 0; p < 8; ++p) {
        const int f = fr + p * 8;
        *reinterpret_cast<float4*>(&B_s[f][c4 * 4]) =
            B4[(kc * BK + f) * (BN_ / 4) + c4];
      }
    } else {           // stage B chunk: 64 x 64
      const int c4 = t & 15, fr = t >> 4;
#pragma unroll
      for (int p = 0; p < 4; ++p) {
        const int f = fr + p * 16;
        *reinterpret_cast<float4*>(&B_s[f][c4 * 4]) =
            B4[(kc * BK + f) * (BN_ / 4) + c4];
      }
    }
    __syncthreads();

#pragma unroll 2
    for (int f = 0; f < BK; ++f) {
      float a[8];
#pragma unroll
      for (int i = 0; i < 8; ++i) a[i] = A_s[m0 + i][f];  // broadcast reads
      float b[CPT];
#pragma unroll
      for (int j4 = 0; j4 < CPT / 4; ++j4) {
        const float4 bv =
            *reinterpret_cast<const float4*>(&B_s[f][c0 + j4 * 4]);
        b[j4 * 4 + 0] = bv.x; b[j4 * 4 + 1] = bv.y;
        b[j4 * 4 + 2] = bv.z; b[j4 * 4 + 3] = bv.w;
      }
#pragma unroll
      for (int i = 0; i < 8; ++i)
#pragma unroll
        for (int j = 0; j < CPT; ++j) acc[i][j] += a[i] * b[j];
    }
  }

#pragma unroll
  for (int i = 0; i < 8; ++i) {
    const int row = bm0 + m0 + i;
    if (row < M) {
      unsigned int words[CPT / 2];
#pragma unroll
      for (int j = 0; j < CPT / 2; ++j) {
        words[j] = (unsigned int)f2bf(acc[i][2 * j]) |
                   ((unsigned int)f2bf(acc[i][2 * j + 1]) << 16);
      }
      unsigned int* dst =
          reinterpret_cast<unsigned int*>(&C[(size_t)row * BN_ + c0]);
#pragma unroll
      for (int j = 0; j < CPT / 2; ++j) dst[j] = words[j];
    }
  }
}

// ---------------- gather-mean over bf16 rows, width 128, fused elu ----------
// 256 threads, 16 nodes/block; node = t>>4 (one per 16-lane group),
// lane l = t&15 covers bytes [16l, 16l+16) = 8 bf16 elements of the row.
// 16 independent dwordx4 gathers per thread.
__global__ __launch_bounds__(256) void gather_mean_128_bf16(
    const unsigned short* __restrict__ Y, const int* __restrict__ idx,
    const float* __restrict__ w, float* __restrict__ out) {
  __shared__ int   idx_s[16][KNBR];
  __shared__ float w_s[16][KNBR];
  const int t = threadIdx.x, n0 = blockIdx.x * 16;
  {
    const int node = t >> 4, k = t & 15;
    const int g = (n0 + node) * (KNBR + 1) + 1 + k;
    idx_s[node][k] = idx[g];
    w_s[node][k]   = w[g];
  }
  __syncthreads();

  const uint4* Y4 = reinterpret_cast<const uint4*>(Y);  // 8 bf16 per uint4
  const int n = t >> 4, l = t & 15;
  float acc[8];
#pragma unroll
  for (int j = 0; j < 8; ++j) acc[j] = 0.f;
#pragma unroll
  for (int k = 0; k < KNBR; ++k) {
    const uint4 v  = Y4[(size_t)idx_s[n][k] * (NF / 8) + l];
    const float wv = w_s[n][k];
    acc[0] += wv * bflo(v.x); acc[1] += wv * bfhi(v.x);
    acc[2] += wv * bflo(v.y); acc[3] += wv * bfhi(v.y);
    acc[4] += wv * bflo(v.z); acc[5] += wv * bfhi(v.z);
    acc[6] += wv * bflo(v.w); acc[7] += wv * bfhi(v.w);
  }
  float4 r0, r1;
#pragma unroll
  for (int j = 0; j < 8; ++j) {
    float v = acc[j] * (1.f / KNBR);
    v = v > 0.f ? v : expm1f(v);  // jax.nn.elu
    (j < 4 ? (&r0.x)[j] : (&r1.x)[j - 4]) = v;
  }
  float4* o4 = reinterpret_cast<float4*>(out);
  o4[((size_t)(n0 + n) * NF + l * 8) / 4]     = r0;
  o4[((size_t)(n0 + n) * NF + l * 8) / 4 + 1] = r1;
}

// ---------------- gather-mean over bf16 rows, width 64, fp32 out ------------
// node = t>>4, lane l = t&15 covers bytes [8l, 8l+8) = 4 bf16 elements.
__global__ __launch_bounds__(256) void gather_mean_64_bf16(
    const unsigned short* __restrict__ Y, const int* __restrict__ idx,
    const float* __restrict__ w, float* __restrict__ out) {
  __shared__ int   idx_s[16][KNBR];
  __shared__ float w_s[16][KNBR];
  const int t = threadIdx.x, n0 = blockIdx.x * 16;
  {
    const int node = t >> 4, k = t & 15;
    const int g = (n0 + node) * (KNBR + 1) + 1 + k;
    idx_s[node][k] = idx[g];
    w_s[node][k]   = w[g];
  }
  __syncthreads();

  const uint2* Y2 = reinterpret_cast<const uint2*>(Y);  // 4 bf16 per uint2
  const int n = t >> 4, l = t & 15;
  float a0 = 0.f, a1 = 0.f, a2 = 0.f, a3 = 0.f;
#pragma unroll
  for (int k = 0; k < KNBR; ++k) {
    const uint2 v  = Y2[(size_t)idx_s[n][k] * (NC / 4) + l];
    const float wv = w_s[n][k];
    a0 += wv * bflo(v.x); a1 += wv * bfhi(v.x);
    a2 += wv * bflo(v.y); a3 += wv * bfhi(v.y);
  }
  reinterpret_cast<float4*>(out)[((size_t)(n0 + n) * NC + l * 4) / 4] =
      make_float4(a0 * (1.f / KNBR), a1 * (1.f / KNBR), a2 * (1.f / KNBR),
                  a3 * (1.f / KNBR));
}

extern "C" void kernel_launch(void* const* d_in, const int* in_sizes, int n_in,
                              void* d_out, int out_size, void* d_ws,
                              size_t ws_size, hipStream_t stream) {
  // 0:x 1:adj1_idx 2:adj1_w1(dead) 3:adj1_w2 4:adj2_idx 5:adj2_w1(dead)
  // 6:adj2_w2 7:W1 8:W2 9..18: relation params (ALL dead)
  const float* x   = (const float*)d_in[0];
  const int*   a1i = (const int*)d_in[1];
  const float* a1w = (const float*)d_in[3];
  const int*   a2i = (const int*)d_in[4];
  const float* a2w = (const float*)d_in[6];
  const float* W1  = (const float*)d_in[7];
  const float* W2  = (const float*)d_in[8];
  float*       out = (float*)d_out;

  unsigned short* Y1 = (unsigned short*)d_ws;                  // 12.8 MB bf16
  float* h1 = (float*)((char*)d_ws + (size_t)NN * NF * 2);     // 25.6 MB fp32
  unsigned short* Y2 = Y1;  // reuse (6.4 MB needed; Y1 dead by then)

  const int gemm_grid = (NN + 127) / 128;  // 391
  gemm_k128_bf16out<NF><<<gemm_grid, 256, 0, stream>>>(x, W1, Y1, NN);
  gather_mean_128_bf16<<<NN / 16, 256, 0, stream>>>(Y1, a1i, a1w, h1);
  gemm_k128_bf16out<NC><<<gemm_grid, 256, 0, stream>>>(h1, W2, Y2, NN);
  gather_mean_64_bf16<<<NN / 16, 256, 0, stream>>>(Y2, a2i, a2w, out);
}

// Round 5
// 65.101 us; speedup vs baseline: 2.0255x; 1.4189x over previous
//
#include <hip/hip_runtime.h>
#include <hip/hip_bf16.h>

// LRGCN_Batch — reference returns ONLY h2, so the _relation() path is dead.
// Live math, REASSOCIATED ((A·x)@W == A·(x@W), A = weighted-mean gather op):
//   Y1 = x @ W1            (bf16 MFMA, fp32 acc, bf16 store)
//   h1 = elu(gather_mean(Y1, adj1_w2))   (fp32 acc, bf16 store)
//   Y2 = h1 @ W2           (bf16 MFMA, fp32 acc, bf16 store)
//   out = gather_mean(Y2, adj2_w2)       (fp32 out)
// R5: GEMMs moved from fp32 VALU (~35-40us combined) to bf16 MFMA (~9us);
// h1 stored bf16 (halves GEMM2 A-read + gather1 write). Gathers (~45us,
// L2-miss-service bound) unchanged. Error budget: each bf16 cast adds
// ~1.5e-5 std at out (mean attenuates x0.14, layer2 matmul x0.57);
// expected absmax ~3e-4 vs 7.7e-4 threshold.

#define NN   50000
#define KNBR 16
#define NF   128   // NFEAT == NHID
#define NC   64    // NCLASS

typedef short s16x8 __attribute__((ext_vector_type(8)));  // 8 bf16 (4 VGPR)
typedef float f32x4 __attribute__((ext_vector_type(4)));

static __device__ __forceinline__ unsigned short f2bf(float f) {
  __hip_bfloat16 h = __float2bfloat16(f);  // RNE
  return reinterpret_cast<unsigned short&>(h);
}
static __device__ __forceinline__ float bflo(unsigned int u) {
  return __uint_as_float(u << 16);
}
static __device__ __forceinline__ float bfhi(unsigned int u) {
  return __uint_as_float(u & 0xffff0000u);
}

// ---------------- MFMA GEMM: C_bf16[M x BN_] = A[M x 128] @ B_f32[128 x BN_]
// 256 threads = 4 waves; block tile 128 rows. Wave w owns rows
// [bm0+32w, bm0+32w+32) as 2 m-tiles of 16. K=128 in 4 steps of 32.
// B staged transposed in LDS as bf16 (Wt[c][k], stride KP=136 -> 16B-aligned
// frag reads, ~2-way banks). mfma_f32_16x16x32_bf16 layouts (m89-verified):
//   A: lane l -> row l&15,  k=(l>>4)*8+{0..7}
//   B: lane l -> col l&15,  k=(l>>4)*8+{0..7}   (= Wt[col][k..k+7], 16B)
//   D: lane l -> col l&15, row=(l>>4)*4+reg
// Epilogue: per-wave LDS transpose tile -> coalesced dwordx4 bf16 stores.
template <int BN_, bool ABF16>
__global__ __launch_bounds__(256, 2) void gemm_mfma(
    const void* __restrict__ Ap, const float* __restrict__ B,
    unsigned short* __restrict__ C, int M) {
  constexpr int CT = BN_ / 16;  // col tiles: 8 or 4
  constexpr int KP = 136;       // LDS row stride in bf16 (272B: 16B-aligned)
  __shared__ unsigned short Wt_s[BN_ * KP];
  __shared__ unsigned short st_s[4][16 * KP];

  const int t = threadIdx.x;
  for (int i = t; i < 128 * BN_; i += 256) {   // stage W^T as bf16
    const int k = i / BN_, c = i % BN_;
    Wt_s[c * KP + k] = f2bf(B[i]);
  }
  __syncthreads();

  const int w   = t >> 6;
  const int l   = t & 63;
  const int lr  = l & 15;   // row-in-mtile (A) / col-in-ctile (B,D)
  const int lk  = l >> 4;   // k-quarter / D row-quad
  const int bm0 = blockIdx.x * 128 + w * 32;

  const int row0 = bm0 + lr, row1 = row0 + 16;
  const int r0c = row0 < M ? row0 : M - 1;  // clamp loads (dup row, safe)
  const int r1c = row1 < M ? row1 : M - 1;

  f32x4 acc[2][CT];
#pragma unroll
  for (int mt = 0; mt < 2; ++mt)
#pragma unroll
    for (int ct = 0; ct < CT; ++ct) acc[mt][ct] = (f32x4){0.f, 0.f, 0.f, 0.f};

#pragma unroll
  for (int ks = 0; ks < 4; ++ks) {
    s16x8 af[2];
    if (ABF16) {
      const uint4* A4 = reinterpret_cast<const uint4*>(Ap);
      af[0] = __builtin_bit_cast(s16x8, A4[(size_t)r0c * (NF / 8) + ks * 4 + lk]);
      af[1] = __builtin_bit_cast(s16x8, A4[(size_t)r1c * (NF / 8) + ks * 4 + lk]);
    } else {
      const float4* A4 = reinterpret_cast<const float4*>(Ap);
      const float4 u0 = A4[(size_t)r0c * 32 + ks * 8 + lk * 2];
      const float4 u1 = A4[(size_t)r0c * 32 + ks * 8 + lk * 2 + 1];
      const float4 v0 = A4[(size_t)r1c * 32 + ks * 8 + lk * 2];
      const float4 v1 = A4[(size_t)r1c * 32 + ks * 8 + lk * 2 + 1];
      unsigned short a0[8] = {f2bf(u0.x), f2bf(u0.y), f2bf(u0.z), f2bf(u0.w),
                              f2bf(u1.x), f2bf(u1.y), f2bf(u1.z), f2bf(u1.w)};
      unsigned short a1[8] = {f2bf(v0.x), f2bf(v0.y), f2bf(v0.z), f2bf(v0.w),
                              f2bf(v1.x), f2bf(v1.y), f2bf(v1.z), f2bf(v1.w)};
      af[0] = __builtin_bit_cast(s16x8, *(uint4*)a0);
      af[1] = __builtin_bit_cast(s16x8, *(uint4*)a1);
    }
    const int kb = ks * 32 + lk * 8;
#pragma unroll
    for (int ct = 0; ct < CT; ++ct) {
      const uint4 bw = *reinterpret_cast<const uint4*>(&Wt_s[(ct * 16 + lr) * KP + kb]);
      const s16x8 bf = __builtin_bit_cast(s16x8, bw);
      acc[0][ct] = __builtin_amdgcn_mfma_f32_16x16x32_bf16(af[0], bf, acc[0][ct], 0, 0, 0);
      acc[1][ct] = __builtin_amdgcn_mfma_f32_16x16x32_bf16(af[1], bf, acc[1][ct], 0, 0, 0);
    }
  }

  unsigned short* st = st_s[w];
#pragma unroll
  for (int mt = 0; mt < 2; ++mt) {
#pragma unroll
    for (int ct = 0; ct < CT; ++ct)
#pragma unroll
      for (int r = 0; r < 4; ++r)
        st[(lk * 4 + r) * KP + ct * 16 + lr] = f2bf(acc[mt][ct][r]);
    // wave-internal LDS readback (compiler inserts lgkmcnt; same wave only)
    if (BN_ == 128) {
#pragma unroll
      for (int p = 0; p < 4; ++p) {
        const int ri = p * 4 + lk;
        const int grow = bm0 + mt * 16 + ri;
        if (grow < M) {
          const uint4 v = *reinterpret_cast<const uint4*>(&st[ri * KP + lr * 8]);
          *reinterpret_cast<uint4*>(&C[(size_t)grow * BN_ + lr * 8]) = v;
        }
      }
    } else {
#pragma unroll
      for (int p = 0; p < 2; ++p) {
        const int ri = p * 8 + (l >> 3);
        const int grow = bm0 + mt * 16 + ri;
        if (grow < M) {
          const uint4 v = *reinterpret_cast<const uint4*>(&st[ri * KP + (l & 7) * 8]);
          *reinterpret_cast<uint4*>(&C[(size_t)grow * BN_ + (l & 7) * 8]) = v;
        }
      }
    }
  }
}

// ---------------- gather-mean over bf16 rows, width 128, elu, bf16 out ------
// 256 threads, 16 nodes/block; node = t>>4, lane l = t&15 covers 8 bf16.
__global__ __launch_bounds__(256) void gather_mean_128_bf16(
    const unsigned short* __restrict__ Y, const int* __restrict__ idx,
    const float* __restrict__ w, unsigned short* __restrict__ out) {
  __shared__ int   idx_s[16][KNBR];
  __shared__ float w_s[16][KNBR];
  const int t = threadIdx.x, n0 = blockIdx.x * 16;
  {
    const int node = t >> 4, k = t & 15;
    const int g = (n0 + node) * (KNBR + 1) + 1 + k;
    idx_s[node][k] = idx[g];
    w_s[node][k]   = w[g];
  }
  __syncthreads();

  const uint4* Y4 = reinterpret_cast<const uint4*>(Y);
  const int n = t >> 4, l = t & 15;
  float acc[8];
#pragma unroll
  for (int j = 0; j < 8; ++j) acc[j] = 0.f;
#pragma unroll
  for (int k = 0; k < KNBR; ++k) {
    const uint4 v  = Y4[(size_t)idx_s[n][k] * (NF / 8) + l];
    const float wv = w_s[n][k];
    acc[0] += wv * bflo(v.x); acc[1] += wv * bfhi(v.x);
    acc[2] += wv * bflo(v.y); acc[3] += wv * bfhi(v.y);
    acc[4] += wv * bflo(v.z); acc[5] += wv * bfhi(v.z);
    acc[6] += wv * bflo(v.w); acc[7] += wv * bfhi(v.w);
  }
  uint4 r;
  unsigned int* rp = &r.x;
#pragma unroll
  for (int j = 0; j < 4; ++j) {
    float a = acc[2 * j] * (1.f / KNBR);
    float b = acc[2 * j + 1] * (1.f / KNBR);
    a = a > 0.f ? a : expm1f(a);  // jax.nn.elu
    b = b > 0.f ? b : expm1f(b);
    rp[j] = (unsigned int)f2bf(a) | ((unsigned int)f2bf(b) << 16);
  }
  reinterpret_cast<uint4*>(out)[(size_t)(n0 + n) * (NF / 8) + l] = r;
}

// ---------------- gather-mean over bf16 rows, width 64, fp32 out ------------
__global__ __launch_bounds__(256) void gather_mean_64_bf16(
    const unsigned short* __restrict__ Y, const int* __restrict__ idx,
    const float* __restrict__ w, float* __restrict__ out) {
  __shared__ int   idx_s[16][KNBR];
  __shared__ float w_s[16][KNBR];
  const int t = threadIdx.x, n0 = blockIdx.x * 16;
  {
    const int node = t >> 4, k = t & 15;
    const int g = (n0 + node) * (KNBR + 1) + 1 + k;
    idx_s[node][k] = idx[g];
    w_s[node][k]   = w[g];
  }
  __syncthreads();

  const uint2* Y2 = reinterpret_cast<const uint2*>(Y);
  const int n = t >> 4, l = t & 15;
  float a0 = 0.f, a1 = 0.f, a2 = 0.f, a3 = 0.f;
#pragma unroll
  for (int k = 0; k < KNBR; ++k) {
    const uint2 v  = Y2[(size_t)idx_s[n][k] * (NC / 4) + l];
    const float wv = w_s[n][k];
    a0 += wv * bflo(v.x); a1 += wv * bfhi(v.x);
    a2 += wv * bflo(v.y); a3 += wv * bfhi(v.y);
  }
  reinterpret_cast<float4*>(out)[(size_t)(n0 + n) * (NC / 4) + l] = make_float4(
      a0 * (1.f / KNBR), a1 * (1.f / KNBR), a2 * (1.f / KNBR),
      a3 * (1.f / KNBR));
}

extern "C" void kernel_launch(void* const* d_in, const int* in_sizes, int n_in,
                              void* d_out, int out_size, void* d_ws,
                              size_t ws_size, hipStream_t stream) {
  // 0:x 1:adj1_idx 2:adj1_w1(dead) 3:adj1_w2 4:adj2_idx 5:adj2_w1(dead)
  // 6:adj2_w2 7:W1 8:W2 9..18: relation params (ALL dead)
  const float* x   = (const float*)d_in[0];
  const int*   a1i = (const int*)d_in[1];
  const float* a1w = (const float*)d_in[3];
  const int*   a2i = (const int*)d_in[4];
  const float* a2w = (const float*)d_in[6];
  const float* W1  = (const float*)d_in[7];
  const float* W2  = (const float*)d_in[8];
  float*       out = (float*)d_out;

  unsigned short* Y1 = (unsigned short*)d_ws;       // 12.8 MB bf16
  unsigned short* h1 = Y1 + (size_t)NN * NF;        // 12.8 MB bf16
  unsigned short* Y2 = Y1;  // reuse (6.4 MB; Y1 dead after gather1)

  const int gg = (NN + 127) / 128;  // 391
  gemm_mfma<NF, false><<<gg, 256, 0, stream>>>(x, W1, Y1, NN);
  gather_mean_128_bf16<<<NN / 16, 256, 0, stream>>>(Y1, a1i, a1w, h1);
  gemm_mfma<NC, true><<<gg, 256, 0, stream>>>(h1, W2, Y2, NN);
  gather_mean_64_bf16<<<NN / 16, 256, 0, stream>>>(Y2, a2i, a2w, out);
}